// Round 4
// baseline (17638.847 us; speedup 1.0000x reference)
//
#include <hip/hip_runtime.h>

// Seq2Seq LSTM (E=256,H=512,B=1024,S=128,T=128). FP32 in/out.
// Round 11: back to relauncher (kernel-boundary coherence = trivially correct)
// with two structural wins over the 14.2ms round-7 baseline:
//  1. Direct-fragment GEMM: mfma_16x16x32 A/B frags are contiguous short8 runs
//     in row-major memory -> load straight from global, NO LDS staging, NO
//     inner-loop barriers. Compiler pipelines 128 loads against 192 MFMAs.
//  2. Vocab-table x-gates: x@Wih^T has only 128 distinct rows (V=128).
//     Precompute xgv[v][2048] in fp32 once; add in the cell. K: 768 -> 512.
// Cell/FC/split numerics verbatim round 7 (verified); h-part MFMA order kept.

typedef unsigned short u16;
typedef __attribute__((ext_vector_type(8))) short short8;
typedef __attribute__((ext_vector_type(4))) float floatx4;

__device__ __forceinline__ float bf2f(u16 s) {
  union { unsigned int u; float f; } v; v.u = ((unsigned int)s) << 16; return v.f;
}
__device__ __forceinline__ u16 f2bf(float x) {
  union { float f; unsigned int u; } v; v.f = x;
  unsigned int r = (v.u + 0x7FFFu + ((v.u >> 16) & 1u)) >> 16;
  return (u16)r;
}
__device__ __forceinline__ void split2(float x, u16* hi, u16* lo) {
  u16 h = f2bf(x);
  *hi = h;
  *lo = f2bf(x - bf2f(h));
}
__device__ __forceinline__ float sigm(float x) { return 1.0f / (1.0f + expf(-x)); }

// ---------------------------------------------------------------- prep ------
__global__ __launch_bounds__(256) void prep_m(
    const float* __restrict__ e_wih, const float* __restrict__ e_whh,
    const float* __restrict__ e_bih, const float* __restrict__ e_bhh,
    const float* __restrict__ d_wih, const float* __restrict__ d_whh,
    const float* __restrict__ d_bih, const float* __restrict__ d_bhh,
    const float* __restrict__ emb, const float* __restrict__ dec_emb,
    const float* __restrict__ fc_w, const float* __restrict__ fc_b,
    u16* __restrict__ WhiE, u16* __restrict__ WloE,
    u16* __restrict__ WhiD, u16* __restrict__ WloD,
    float* __restrict__ bcE, float* __restrict__ bcD,
    float* __restrict__ xgvE, float* __restrict__ xgvD,
    float* __restrict__ fwT, float* __restrict__ fcb,
    u16* __restrict__ hHi, u16* __restrict__ hLo,
    float* __restrict__ c, float* __restrict__ out) {
  int idx0 = blockIdx.x * blockDim.x + threadIdx.x;
  int stride = gridDim.x * blockDim.x;
  // recurrent weights, interleaved gate rows (rr = unit*4 + gate), K=512
  for (int i = idx0; i < 2048 * 512; i += stride) {
    int rr = i >> 9, k = i & 511;
    int j = rr >> 2, g = rr & 3;
    int orig = g * 512 + j;  // reference gate order i,f,g,o
    split2(e_whh[orig * 512 + k], &WhiE[i], &WloE[i]);
    split2(d_whh[orig * 512 + k], &WhiD[i], &WloD[i]);
  }
  for (int i = idx0; i < 2048; i += stride) {
    int j = i >> 2, g = i & 3, orig = g * 512 + j;
    bcE[i] = e_bih[orig] + e_bhh[orig];
    bcD[i] = d_bih[orig] + d_bhh[orig];
  }
  // vocab x-gate tables: xgv[v][rr] = dot(emb[v], wih[orig]) in fp32
  for (int i = idx0; i < 2 * 128 * 2048; i += stride) {
    int ph = (i >= 128 * 2048) ? 1 : 0;
    int ii = ph ? i - 128 * 2048 : i;
    int v = ii >> 11, rr = ii & 2047;
    int j = rr >> 2, g = rr & 3;
    int orig = g * 512 + j;
    const float* er = (ph ? dec_emb : emb) + v * 256;
    const float* wr = (ph ? d_wih : e_wih) + orig * 256;
    float s = 0.0f;
#pragma unroll 4
    for (int e = 0; e < 256; e += 4) {
      floatx4 ev = *(const floatx4*)(er + e);
      floatx4 wv = *(const floatx4*)(wr + e);
      s += ev[0] * wv[0] + ev[1] * wv[1] + ev[2] * wv[2] + ev[3] * wv[3];
    }
    (ph ? xgvD : xgvE)[v * 2048 + rr] = s;
  }
  for (int i = idx0; i < 128 * 512; i += stride) {
    int v = i >> 9, k = i & 511;
    fwT[k * 128 + v] = fc_w[i];
  }
  for (int i = idx0; i < 128; i += stride) fcb[i] = fc_b[i];
  for (int i = idx0; i < 1024 * 512; i += stride) {
    hHi[i] = 0; hLo[i] = 0; c[i] = 0.0f;
  }
  for (int i = idx0; i < 1024 * 128; i += stride)
    out[(i >> 7) * 16384 + (i & 127)] = 0.0f;  // out[:,0,:] = 0
}

// ------------------------------------------------------------ lstm step -----
// grid (32,16): bx -> n0 (interleaved gate cols), by -> m0 (batch). 256 thr.
// 64x64 tile, 4 waves, 2x2 MFMA 16x16x32, 3-term hi/lo split, K=512 (h only).
// Fragments loaded DIRECTLY from global (contiguous short8 runs) - no LDS
// staging, no inner-loop barriers.
__global__ __launch_bounds__(256) void lstm_step_d(
    const int* __restrict__ idx, int t,
    const u16* __restrict__ Whi, const u16* __restrict__ Wlo,  // (2048,512)
    const float* __restrict__ xgv,                             // (128,2048)
    const float* __restrict__ bc,                              // (2048)
    const u16* __restrict__ hHi_in, const u16* __restrict__ hLo_in,
    u16* __restrict__ hHi_out, u16* __restrict__ hLo_out,
    float* __restrict__ c) {
  __shared__ __align__(16) float gl[64 * 68];  // gate exchange, 17408 B
  __shared__ int sidx[64];
  const int tid = threadIdx.x;
  const int m0 = blockIdx.y * 64;
  const int n0 = blockIdx.x * 64;
  if (tid < 64) sidx[tid] = idx[(m0 + tid) * 128 + t];

  const int lane = tid & 63;
  const int wv = tid >> 6;
  const int wm = wv & 1, wn = wv >> 1;
  const int lr = lane & 15, lq = lane >> 4;
  const int ra0 = wm * 32 + lr, ra1 = ra0 + 16;
  const int rb0 = wn * 32 + lr, rb1 = rb0 + 16;

  // per-lane fragment base pointers (advance by imm offsets in the loop)
  const u16* pah0 = hHi_in + (m0 + ra0) * 512 + lq * 8;
  const u16* pah1 = hHi_in + (m0 + ra1) * 512 + lq * 8;
  const u16* pal0 = hLo_in + (m0 + ra0) * 512 + lq * 8;
  const u16* pal1 = hLo_in + (m0 + ra1) * 512 + lq * 8;
  const u16* pbh0 = Whi + (n0 + rb0) * 512 + lq * 8;
  const u16* pbh1 = Whi + (n0 + rb1) * 512 + lq * 8;
  const u16* pbl0 = Wlo + (n0 + rb0) * 512 + lq * 8;
  const u16* pbl1 = Wlo + (n0 + rb1) * 512 + lq * 8;

  floatx4 acc00 = {0.f, 0.f, 0.f, 0.f}, acc01 = {0.f, 0.f, 0.f, 0.f};
  floatx4 acc10 = {0.f, 0.f, 0.f, 0.f}, acc11 = {0.f, 0.f, 0.f, 0.f};

#pragma unroll
  for (int kk = 0; kk < 16; ++kk) {
    const int k = kk * 32;
    short8 ah0 = *(const short8*)(pah0 + k);
    short8 ah1 = *(const short8*)(pah1 + k);
    short8 al0 = *(const short8*)(pal0 + k);
    short8 al1 = *(const short8*)(pal1 + k);
    short8 bh0 = *(const short8*)(pbh0 + k);
    short8 bh1 = *(const short8*)(pbh1 + k);
    short8 bl0 = *(const short8*)(pbl0 + k);
    short8 bl1 = *(const short8*)(pbl1 + k);
    acc00 = __builtin_amdgcn_mfma_f32_16x16x32_bf16(al0, bh0, acc00, 0, 0, 0);
    acc00 = __builtin_amdgcn_mfma_f32_16x16x32_bf16(ah0, bl0, acc00, 0, 0, 0);
    acc00 = __builtin_amdgcn_mfma_f32_16x16x32_bf16(ah0, bh0, acc00, 0, 0, 0);
    acc01 = __builtin_amdgcn_mfma_f32_16x16x32_bf16(al0, bh1, acc01, 0, 0, 0);
    acc01 = __builtin_amdgcn_mfma_f32_16x16x32_bf16(ah0, bl1, acc01, 0, 0, 0);
    acc01 = __builtin_amdgcn_mfma_f32_16x16x32_bf16(ah0, bh1, acc01, 0, 0, 0);
    acc10 = __builtin_amdgcn_mfma_f32_16x16x32_bf16(al1, bh0, acc10, 0, 0, 0);
    acc10 = __builtin_amdgcn_mfma_f32_16x16x32_bf16(ah1, bl0, acc10, 0, 0, 0);
    acc10 = __builtin_amdgcn_mfma_f32_16x16x32_bf16(ah1, bh0, acc10, 0, 0, 0);
    acc11 = __builtin_amdgcn_mfma_f32_16x16x32_bf16(al1, bh1, acc11, 0, 0, 0);
    acc11 = __builtin_amdgcn_mfma_f32_16x16x32_bf16(ah1, bl1, acc11, 0, 0, 0);
    acc11 = __builtin_amdgcn_mfma_f32_16x16x32_bf16(ah1, bh1, acc11, 0, 0, 0);
  }

  // gates -> LDS fp32 (stride 68 floats)
  const int rowb = wm * 32 + lq * 4;
  const int colb = wn * 32 + lr;
#pragma unroll
  for (int j = 0; j < 4; ++j) {
    gl[(rowb + j) * 68 + colb] = acc00[j];
    gl[(rowb + j) * 68 + colb + 16] = acc01[j];
    gl[(rowb + 16 + j) * 68 + colb] = acc10[j];
    gl[(rowb + 16 + j) * 68 + colb + 16] = acc11[j];
  }
  __syncthreads();

  // fused LSTM cell: 64 rows x 16 units per block; gates = h-part (MFMA) +
  // x-part (vocab table, fp32) + combined bias.
#pragma unroll
  for (int ii = 0; ii < 4; ++ii) {
    int pp = ii * 256 + tid;
    int row = pp >> 4;
    int u = pp & 15;
    const float* gp = gl + row * 68 + u * 4;
    floatx4 bg = *(const floatx4*)(bc + n0 + u * 4);
    floatx4 xg = *(const floatx4*)(xgv + sidx[row] * 2048 + n0 + u * 4);
    float gi = gp[0] + bg[0] + xg[0];
    float gf = gp[1] + bg[1] + xg[1];
    float gg = gp[2] + bg[2] + xg[2];
    float go = gp[3] + bg[3] + xg[3];
    int ci = (m0 + row) * 512 + (n0 >> 2) + u;
    float cold = c[ci];
    float cn = sigm(gf) * cold + sigm(gi) * tanhf(gg);
    c[ci] = cn;
    float h = sigm(go) * tanhf(cn);
    u16 hi, lo;
    split2(h, &hi, &lo);
    hHi_out[ci] = hi;
    hLo_out[ci] = lo;
  }
}

// --------------------------------------------------------------- fc step ----
// out[:, t+1, :] = h @ fc_w^T + fc_b (h = hi + lo planes). grid (128), 256 thr.
// Verbatim from verified round-7 kernel.
__global__ __launch_bounds__(256) void fc_step_v(
    const u16* __restrict__ hHi, const u16* __restrict__ hLo,  // (1024,512)
    const float* __restrict__ fwT,  // (512,128) = fc_w^T
    const float* __restrict__ fcb,  // (128)
    float* __restrict__ out, int t) {
  __shared__ float smH[4096];  // 8 rows x 512; reused as reduce scratch
  const int tid = threadIdx.x;
  const int b0 = blockIdx.x * 8;
  {
    int o = b0 * 512 + tid * 16;
    short8 vh = *(const short8*)(hHi + o);
    short8 vl = *(const short8*)(hLo + o);
    short8 vh2 = *(const short8*)(hHi + o + 8);
    short8 vl2 = *(const short8*)(hLo + o + 8);
    float* d = &smH[tid * 16];
#pragma unroll
    for (int j = 0; j < 8; ++j) d[j] = bf2f((u16)vh[j]) + bf2f((u16)vl[j]);
#pragma unroll
    for (int j = 0; j < 8; ++j) d[8 + j] = bf2f((u16)vh2[j]) + bf2f((u16)vl2[j]);
  }
  __syncthreads();

  const int v = tid & 127;
  const int half = tid >> 7;
  float acc[8];
#pragma unroll
  for (int r0 = 0; r0 < 8; ++r0) acc[r0] = 0.0f;
  const int kbase = half * 256;
  for (int k = kbase; k < kbase + 256; ++k) {
    float w = fwT[k * 128 + v];
#pragma unroll
    for (int r0 = 0; r0 < 8; ++r0) acc[r0] += smH[r0 * 512 + k] * w;
  }
  __syncthreads();
  float* red = smH;
#pragma unroll
  for (int r0 = 0; r0 < 8; ++r0) red[half * 1024 + r0 * 128 + v] = acc[r0];
  __syncthreads();
  if (half == 0) {
    float bias = fcb[v];
#pragma unroll
    for (int r0 = 0; r0 < 8; ++r0) {
      float sum = red[r0 * 128 + v] + red[1024 + r0 * 128 + v] + bias;
      out[(b0 + r0) * 16384 + (t + 1) * 128 + v] = sum;
    }
  }
}

// ---------------------------------------------------------------- launch ----
extern "C" void kernel_launch(void* const* d_in, const int* in_sizes, int n_in,
                              void* d_out, int out_size, void* d_ws, size_t ws_size,
                              hipStream_t stream) {
  const int* src = (const int*)d_in[0];
  const int* tgt = (const int*)d_in[1];
  const float* emb = (const float*)d_in[2];
  const float* dec_emb = (const float*)d_in[3];
  const float* e_wih = (const float*)d_in[4];
  const float* e_whh = (const float*)d_in[5];
  const float* e_bih = (const float*)d_in[6];
  const float* e_bhh = (const float*)d_in[7];
  const float* d_wih = (const float*)d_in[8];
  const float* d_whh = (const float*)d_in[9];
  const float* d_bih = (const float*)d_in[10];
  const float* d_bhh = (const float*)d_in[11];
  const float* fc_w = (const float*)d_in[12];
  const float* fc_b = (const float*)d_in[13];
  float* out = (float*)d_out;

  char* ws = (char*)d_ws;
  u16* WhiE = (u16*)(ws + 0);              // 2,097,152
  u16* WloE = (u16*)(ws + 2097152);        // 2,097,152
  u16* WhiD = (u16*)(ws + 4194304);        // 2,097,152
  u16* WloD = (u16*)(ws + 6291456);        // 2,097,152
  float* bcE = (float*)(ws + 8388608);     // 8,192
  float* bcD = (float*)(ws + 8396800);     // 8,192
  float* xgvE = (float*)(ws + 8404992);    // 1,048,576
  float* xgvD = (float*)(ws + 9453568);    // 1,048,576
  float* fwT = (float*)(ws + 10502144);    // 262,144
  float* fcb = (float*)(ws + 10764288);    // 512
  u16* hHiA = (u16*)(ws + 10764800);       // 1,048,576
  u16* hLoA = (u16*)(ws + 11813376);       // 1,048,576
  u16* hHiB = (u16*)(ws + 12861952);       // 1,048,576
  u16* hLoB = (u16*)(ws + 13910528);       // 1,048,576
  float* cbuf = (float*)(ws + 14959104);   // 2,097,152  (total ~17.1 MB)

  prep_m<<<1024, 256, 0, stream>>>(e_wih, e_whh, e_bih, e_bhh,
                                   d_wih, d_whh, d_bih, d_bhh,
                                   emb, dec_emb, fc_w, fc_b,
                                   WhiE, WloE, WhiD, WloD, bcE, bcD,
                                   xgvE, xgvD, fwT, fcb,
                                   hHiA, hLoA, cbuf, out);

  dim3 gstep(32, 16);
  const u16* hHi_in = hHiA; const u16* hLo_in = hLoA;
  u16* hHi_out = hHiB; u16* hLo_out = hLoB;
  for (int t = 0; t < 128; ++t) {
    lstm_step_d<<<gstep, 256, 0, stream>>>(src, t, WhiE, WloE, xgvE, bcE,
                                           hHi_in, hLo_in, hHi_out, hLo_out,
                                           cbuf);
    const u16* th = hHi_out; hHi_out = (u16*)hHi_in; hHi_in = th;
    const u16* tl = hLo_out; hLo_out = (u16*)hLo_in; hLo_in = tl;
  }
  for (int t = 0; t < 127; ++t) {
    lstm_step_d<<<gstep, 256, 0, stream>>>(tgt, t, WhiD, WloD, xgvD, bcD,
                                           hHi_in, hLo_in, hHi_out, hLo_out,
                                           cbuf);
    const u16* th = hHi_out; hHi_out = (u16*)hHi_in; hHi_in = th;
    const u16* tl = hLo_out; hLo_out = (u16*)hLo_in; hLo_in = tl;
    fc_step_v<<<128, 256, 0, stream>>>(hHi_in, hLo_in, fwT, fcb, out, t);
  }
}